// Round 7
// baseline (323.794 us; speedup 1.0000x reference)
//
#include <hip/hip_runtime.h>
#include <math.h>

#define D 4096
#define NSLOTS 128
#define TR 8192
#define EPS_TRIG 5e-5f
#define WIN 2e-5f

typedef __attribute__((ext_vector_type(8))) short bf16x8;
typedef __attribute__((ext_vector_type(4))) float f32x4;

union BV { bf16x8 v; unsigned u[4]; };

__device__ __forceinline__ unsigned short bfrne(float x) {
  unsigned u = __float_as_uint(x);
  unsigned r = u + 0x7fffu + ((u >> 16) & 1u);   // round-to-nearest-even
  return (unsigned short)(r >> 16);
}

// ---- Kernel A: EMA write + produce M bf16 hi/mid planes (row-major + T) ----
__global__ __launch_bounds__(256) void update_mem_kernel(
    const float* __restrict__ values, const float* __restrict__ memory,
    const float* __restrict__ gate_w, const float* __restrict__ gate_b,
    const int* __restrict__ layer_idx_p, const int* __restrict__ ptr_p,
    int T_W, float* __restrict__ ws_mem,
    unsigned short* __restrict__ Mh, unsigned short* __restrict__ Mm,
    unsigned short* __restrict__ Mth, unsigned short* __restrict__ Mtm) {
  const int l = layer_idx_p[0], p = ptr_p[0], s = blockIdx.x, tid = threadIdx.x;
  int t0 = ((s - p) % NSLOTS + NSLOTS) % NSLOTS;
  const bool written = (t0 < T_W);
  const int t = written ? (t0 + ((T_W - 1 - t0) / NSLOTS) * NSLOTS) : 0; // last write wins
  const float* mrow = memory + ((size_t)l * NSLOTS + s) * D;
  const float* vrow = values + (size_t)t * D;

  float acoef = 0.f, bcoef = 1.0f;
  if (written) {
    const float* gw = gate_w + (size_t)l * D;
    double acc = 0.0;
    for (int j = tid; j < D; j += 256)
      acc += (double)vrow[j] * (double)gw[j];
    for (int off = 32; off; off >>= 1) acc += __shfl_down(acc, off, 64);
    __shared__ double wsum[4];
    if ((tid & 63) == 0) wsum[tid >> 6] = acc;
    __syncthreads();
    double dot = wsum[0] + wsum[1] + wsum[2] + wsum[3];
    float x = (float)dot + gate_b[l];
    float g = 1.0f / (1.0f + expf(-x));
    acoef = 0.1f * g; bcoef = 0.9f;
  }

  for (int j4 = tid; j4 < D / 4; j4 += 256) {
    float4 mv = ((const float4*)mrow)[j4];
    float4 vv = make_float4(0.f, 0.f, 0.f, 0.f);
    if (written) vv = ((const float4*)vrow)[j4];
    float ov[4];
    ov[0] = acoef * vv.x + bcoef * mv.x;
    ov[1] = acoef * vv.y + bcoef * mv.y;
    ov[2] = acoef * vv.z + bcoef * mv.z;
    ov[3] = acoef * vv.w + bcoef * mv.w;
    ((float4*)(ws_mem + (size_t)s * D))[j4] =
        make_float4(ov[0], ov[1], ov[2], ov[3]);
    unsigned short h[4], md[4];
#pragma unroll
    for (int e = 0; e < 4; ++e) {
      h[e] = bfrne(ov[e]);
      float f = __uint_as_float((unsigned)h[e] << 16);
      md[e] = bfrne(ov[e] - f);
    }
    uint2 hp = make_uint2((unsigned)h[0] | ((unsigned)h[1] << 16),
                          (unsigned)h[2] | ((unsigned)h[3] << 16));
    uint2 mp = make_uint2((unsigned)md[0] | ((unsigned)md[1] << 16),
                          (unsigned)md[2] | ((unsigned)md[3] << 16));
    ((uint2*)Mh)[(size_t)s * (D / 4) + j4] = hp;
    ((uint2*)Mm)[(size_t)s * (D / 4) + j4] = mp;
#pragma unroll
    for (int e = 0; e < 4; ++e) {
      Mth[(size_t)(j4 * 4 + e) * NSLOTS + s] = h[e];
      Mtm[(size_t)(j4 * 4 + e) * NSLOTS + s] = md[e];
    }
  }
}

// ---- Kernel B: partial scores, tileQ=64 x splitK=8, reg-pipelined ----------
// grid = (TR/64) * 8 = 1024 blocks x 256 thr. Block (qt,kq): rows qt*64..+64,
// K range kq*512..+512, all 128 slots. Wave w: rows +w*16. No LDS, no barrier.
// Double-buffered register staging, prefetch distance 2 (16 K-steps total).
__global__ __launch_bounds__(256) void scores_kernel(
    const float* __restrict__ queries, const unsigned short* __restrict__ Mh,
    const unsigned short* __restrict__ Mm, float* __restrict__ part) {
  const int tid = threadIdx.x, lane = tid & 63, w = tid >> 6;
  const int fr = lane & 15, fo = lane >> 4;
  const int qt = blockIdx.x >> 3, kq = blockIdx.x & 7;
  const int row0 = qt * 64 + w * 16;
  const int kbase = kq * 512;

  const float* qp = queries + (size_t)(row0 + fr) * D + kbase + fo * 8;
  const unsigned short* mhp = Mh + (size_t)fr * D + kbase + fo * 8;
  const unsigned short* mmp = Mm + (size_t)fr * D + kbase + fo * 8;

  f32x4 acc[8];
#pragma unroll
  for (int g = 0; g < 8; ++g) acc[g] = (f32x4){0.f, 0.f, 0.f, 0.f};

  bf16x8 BHb[2][8], BMb[2][8];
  float4 QAb[2], QBb[2];

  // prologue: fill both pipeline stages (K-steps 0 and 1)
#pragma unroll
  for (int s = 0; s < 2; ++s) {
    QAb[s] = *(const float4*)(qp + s * 32);
    QBb[s] = *(const float4*)(qp + s * 32 + 4);
#pragma unroll
    for (int g = 0; g < 8; ++g) {
      BHb[s][g] = *(const bf16x8*)(mhp + (size_t)g * 16 * D + s * 32);
      BMb[s][g] = *(const bf16x8*)(mmp + (size_t)g * 16 * D + s * 32);
    }
  }

#pragma unroll 2
  for (int it = 0; it < 16; ++it) {
    const int cur = it & 1;          // compile-time under unroll 2
    const int kpre = it * 32 + 64;   // K-offset being prefetched (it+2)
    const bool pre = (kpre < 512);

    // split q (consumes QAb[cur]/QBb[cur], loaded 2 iterations ago)
    float qf[8] = {QAb[cur].x, QAb[cur].y, QAb[cur].z, QAb[cur].w,
                   QBb[cur].x, QBb[cur].y, QBb[cur].z, QBb[cur].w};
    // prefetch q for it+2 (overwrites cur after consumption above)
    if (pre) {
      QAb[cur] = *(const float4*)(qp + kpre);
      QBb[cur] = *(const float4*)(qp + kpre + 4);
    }
    BV ah, am;
#pragma unroll
    for (int i = 0; i < 4; ++i) {
      unsigned u0 = __float_as_uint(qf[2 * i]);
      unsigned u1 = __float_as_uint(qf[2 * i + 1]);
      ah.u[i] = (u0 >> 16) | (u1 & 0xffff0000u);     // truncated hi
      float f0 = __uint_as_float(u0 & 0xffff0000u);
      float f1 = __uint_as_float(u1 & 0xffff0000u);
      unsigned d0 = __float_as_uint(qf[2 * i] - f0);
      unsigned d1 = __float_as_uint(qf[2 * i + 1] - f1);
      am.u[i] = (d0 >> 16) | (d1 & 0xffff0000u);     // truncated mid
    }

#pragma unroll
    for (int g = 0; g < 8; ++g) {
      bf16x8 bh = BHb[cur][g];
      bf16x8 bm = BMb[cur][g];
      // prefetch B for it+2 into the slot just freed (WAR-safe: in-order issue)
      if (pre) {
        BHb[cur][g] = *(const bf16x8*)(mhp + (size_t)g * 16 * D + kpre);
        BMb[cur][g] = *(const bf16x8*)(mmp + (size_t)g * 16 * D + kpre);
      }
      acc[g] = __builtin_amdgcn_mfma_f32_16x16x32_bf16(am.v, bh, acc[g], 0, 0, 0);
      acc[g] = __builtin_amdgcn_mfma_f32_16x16x32_bf16(ah.v, bm, acc[g], 0, 0, 0);
      acc[g] = __builtin_amdgcn_mfma_f32_16x16x32_bf16(ah.v, bh, acc[g], 0, 0, 0);
    }
  }

  float* op = part + ((size_t)kq * TR + row0) * NSLOTS;
#pragma unroll
  for (int g = 0; g < 8; ++g)
#pragma unroll
    for (int r = 0; r < 4; ++r)
      op[(size_t)(fo * 4 + r) * NSLOTS + g * 16 + fr] = acc[g][r];
}

// ---- Kernel C: wave-per-row reduce-partials -> top-k -> softmax -> A planes --
__device__ __forceinline__ unsigned mapf(float f) {
  unsigned u = __float_as_uint(f);
  return (u & 0x80000000u) ? ~u : (u | 0x80000000u);
}
__device__ __forceinline__ float unmapf(unsigned u) {
  return __uint_as_float((u & 0x80000000u) ? (u & 0x7fffffffu) : ~u);
}

__device__ __forceinline__ void wave_select(
    float va, float vb, int l, int k, int iters,
    float &m, float &sum, bool &sela, bool &selb, float &vkm1, float &vkk) {
  m = 0.f; sum = 0.f; sela = false; selb = false; vkm1 = 0.f; vkk = -3.4e38f;
  for (int it = 0; it < iters; ++it) {
    unsigned long long ka =
        ((unsigned long long)mapf(va) << 32) | (unsigned)(127 - l);
    unsigned long long kb =
        ((unsigned long long)mapf(vb) << 32) | (unsigned)(63 - l);
    unsigned long long key = ka > kb ? ka : kb;
#pragma unroll
    for (int off = 32; off; off >>= 1) {
      unsigned long long o = __shfl_xor(key, off, 64);
      if (o > key) key = o;
    }
    int idx = 127 - (int)(unsigned)(key & 0xffffffffULL);
    float val = unmapf((unsigned)(key >> 32));
    if (it == 0) m = val;
    if (it < k) sum += expf(val - m);
    if (it == k - 1) vkm1 = val;
    if (it == k) vkk = val;
    if (idx == l) { sela = sela || (it < k); va = -INFINITY; }
    if (idx == l + 64) { selb = selb || (it < k); vb = -INFINITY; }
  }
}

__device__ __forceinline__ float rescore_slot(const float* __restrict__ qrow,
                                              const float* __restrict__ mrow,
                                              int l) {
  double acc = 0.0;
#pragma unroll 4
  for (int c = 0; c < 16; ++c) {
    int j = c * 256 + l * 4;
    float4 qv = *(const float4*)(qrow + j);
    float4 mv = *(const float4*)(mrow + j);
    acc += (double)qv.x * (double)mv.x;
    acc += (double)qv.y * (double)mv.y;
    acc += (double)qv.z * (double)mv.z;
    acc += (double)qv.w * (double)mv.w;
  }
#pragma unroll
  for (int off = 32; off; off >>= 1) acc += __shfl_xor(acc, off, 64);
  return (float)(acc * 0.015625);
}

__global__ __launch_bounds__(256) void topk_kernel(
    const float* __restrict__ part, const float* __restrict__ ws_mem,
    const float* __restrict__ queries, const int* __restrict__ k_p,
    unsigned short* __restrict__ Ah, unsigned short* __restrict__ Am) {
  const int w = threadIdx.x >> 6, l = threadIdx.x & 63;
  const int row = blockIdx.x * 4 + w;
  int k = k_p[0];
  if (k < 1) k = 1;
  if (k > NSLOTS) k = NSLOTS;
  const int ksel = (k < NSLOTS) ? k + 1 : k;

  float origa = 0.f, origb = 0.f;
#pragma unroll
  for (int kq = 0; kq < 8; ++kq) {
    origa += part[((size_t)kq * TR + row) * NSLOTS + l];
    origb += part[((size_t)kq * TR + row) * NSLOTS + 64 + l];
  }
  origa *= 0.015625f;   // 1/sqrt(4096)
  origb *= 0.015625f;

  float m, sum, vkm1, vkk;
  bool sela, selb;
  wave_select(origa, origb, l, k, ksel, m, sum, sela, selb, vkm1, vkk);

  if (ksel > k && (vkm1 - vkk) < EPS_TRIG) {
    // exact fp64 rescore of boundary-window slots only (set membership fix)
    const float* qrow = queries + (size_t)row * D;
    float lo = vkk - WIN, hi = vkm1 + WIN;
    unsigned long long ba = __ballot(origa >= lo && origa <= hi);
    unsigned long long bb = __ballot(origb >= lo && origb <= hi);
    while (ba) {
      int s = __ffsll(ba) - 1; ba &= ba - 1;
      float ex = rescore_slot(qrow, ws_mem + (size_t)s * D, l);
      if (l == s) origa = ex;
    }
    while (bb) {
      int s = __ffsll(bb) - 1; bb &= bb - 1;
      float ex = rescore_slot(qrow, ws_mem + (size_t)(s + 64) * D, l);
      if (l == s) origb = ex;
    }
    wave_select(origa, origb, l, k, k, m, sum, sela, selb, vkm1, vkk);
  }

  const float inv = 1.0f / sum;
  float wa = sela ? expf(origa - m) * inv : 0.f;
  float wb = selb ? expf(origb - m) * inv : 0.f;

  unsigned short ha = bfrne(wa);
  unsigned short ma = bfrne(wa - __uint_as_float((unsigned)ha << 16));
  unsigned short hb = bfrne(wb);
  unsigned short mb = bfrne(wb - __uint_as_float((unsigned)hb << 16));
  Ah[(size_t)row * NSLOTS + l] = ha;
  Am[(size_t)row * NSLOTS + l] = ma;
  Ah[(size_t)row * NSLOTS + 64 + l] = hb;
  Am[(size_t)row * NSLOTS + 64 + l] = mb;
}

// ---- Kernel D: out = A @ mem_new as dense bf16-split GEMM (K=128) ----
__global__ __launch_bounds__(256) void gather_kernel(
    const unsigned short* __restrict__ Ah, const unsigned short* __restrict__ Am,
    const unsigned short* __restrict__ Mth, const unsigned short* __restrict__ Mtm,
    float* __restrict__ out) {
  const int tid = threadIdx.x, lane = tid & 63, w = tid >> 6;
  const int fr = lane & 15, fo = lane >> 4;
  const int rowblk = blockIdx.x >> 5, colblk = blockIdx.x & 31;
  const int r0 = rowblk * 64 + w * 16;

  const unsigned short* ap_h = Ah + (size_t)(r0 + fr) * NSLOTS + fo * 8;
  const unsigned short* ap_m = Am + (size_t)(r0 + fr) * NSLOTS + fo * 8;
  bf16x8 a_h[4], a_m[4];
#pragma unroll
  for (int c = 0; c < 4; ++c) {
    a_h[c] = *(const bf16x8*)(ap_h + c * 32);
    a_m[c] = *(const bf16x8*)(ap_m + c * 32);
  }

#pragma unroll 2
  for (int ct = 0; ct < 8; ++ct) {
    const int col = colblk * 128 + ct * 16 + fr;
    const unsigned short* bp_h = Mth + (size_t)col * NSLOTS + fo * 8;
    const unsigned short* bp_m = Mtm + (size_t)col * NSLOTS + fo * 8;
    f32x4 acc = {0.f, 0.f, 0.f, 0.f};
#pragma unroll
    for (int c = 0; c < 4; ++c) {
      bf16x8 bh = *(const bf16x8*)(bp_h + c * 32);
      bf16x8 bm = *(const bf16x8*)(bp_m + c * 32);
      acc = __builtin_amdgcn_mfma_f32_16x16x32_bf16(a_m[c], bh, acc, 0, 0, 0);
      acc = __builtin_amdgcn_mfma_f32_16x16x32_bf16(a_h[c], bm, acc, 0, 0, 0);
      acc = __builtin_amdgcn_mfma_f32_16x16x32_bf16(a_h[c], bh, acc, 0, 0, 0);
    }
#pragma unroll
    for (int r = 0; r < 4; ++r)
      out[(size_t)(r0 + fo * 4 + r) * D + col] = acc[r];
  }
}

extern "C" void kernel_launch(void* const* d_in, const int* in_sizes, int n_in,
                              void* d_out, int out_size, void* d_ws, size_t ws_size,
                              hipStream_t stream) {
  const float* values  = (const float*)d_in[0];
  const float* queries = (const float*)d_in[1];
  const float* memory  = (const float*)d_in[2];
  const float* gate_w  = (const float*)d_in[3];
  const float* gate_b  = (const float*)d_in[4];
  const int* layer_idx = (const int*)d_in[5];
  const int* k_p       = (const int*)d_in[6];
  const int* ptr_p     = (const int*)d_in[7];

  const int T_W = in_sizes[0] / D;   // 128
  const int T_R = in_sizes[1] / D;   // 8192

  float* ws_mem = (float*)d_ws;                              // 2 MiB
  float* part   = ws_mem + (size_t)NSLOTS * D;               // 8 planes, 32 MiB
  unsigned short* Mh  = (unsigned short*)(part + (size_t)8 * TR * NSLOTS);
  unsigned short* Mm  = Mh  + (size_t)NSLOTS * D;            // 1 MiB each
  unsigned short* Mth = Mm  + (size_t)NSLOTS * D;
  unsigned short* Mtm = Mth + (size_t)NSLOTS * D;
  unsigned short* Ah  = Mtm + (size_t)NSLOTS * D;            // 2 MiB each
  unsigned short* Am  = Ah  + (size_t)T_R * NSLOTS;

  update_mem_kernel<<<NSLOTS, 256, 0, stream>>>(
      values, memory, gate_w, gate_b, layer_idx, ptr_p, T_W,
      ws_mem, Mh, Mm, Mth, Mtm);
  scores_kernel<<<(T_R / 64) * 8, 256, 0, stream>>>(queries, Mh, Mm, part);
  topk_kernel<<<T_R / 4, 256, 0, stream>>>(part, ws_mem, queries, k_p, Ah, Am);
  gather_kernel<<<(T_R / 64) * 32, 256, 0, stream>>>(Ah, Am, Mth, Mtm,
                                                     (float*)d_out);
}

// Round 8
// 230.163 us; speedup vs baseline: 1.4068x; 1.4068x over previous
//
#include <hip/hip_runtime.h>
#include <math.h>

#define D 4096
#define NSLOTS 128
#define TR 8192
#define EPS_TRIG 5e-5f
#define WIN 2e-5f

typedef __attribute__((ext_vector_type(8))) short bf16x8;
typedef __attribute__((ext_vector_type(4))) float f32x4;

union BV { bf16x8 v; unsigned u[4]; };

__device__ __forceinline__ unsigned short bfrne(float x) {
  unsigned u = __float_as_uint(x);
  unsigned r = u + 0x7fffu + ((u >> 16) & 1u);   // round-to-nearest-even
  return (unsigned short)(r >> 16);
}

__device__ __forceinline__ void gload16(const void* gsrc, void* ldst) {
  __builtin_amdgcn_global_load_lds(
      (const __attribute__((address_space(1))) void*)gsrc,
      (__attribute__((address_space(3))) void*)ldst, 16, 0, 0);
}

// ---- Kernel A: EMA write + produce M bf16 hi/mid planes (row-major + T) ----
__global__ __launch_bounds__(256) void update_mem_kernel(
    const float* __restrict__ values, const float* __restrict__ memory,
    const float* __restrict__ gate_w, const float* __restrict__ gate_b,
    const int* __restrict__ layer_idx_p, const int* __restrict__ ptr_p,
    int T_W, float* __restrict__ ws_mem,
    unsigned short* __restrict__ Mh, unsigned short* __restrict__ Mm,
    unsigned short* __restrict__ Mth, unsigned short* __restrict__ Mtm) {
  const int l = layer_idx_p[0], p = ptr_p[0], s = blockIdx.x, tid = threadIdx.x;
  int t0 = ((s - p) % NSLOTS + NSLOTS) % NSLOTS;
  const bool written = (t0 < T_W);
  const int t = written ? (t0 + ((T_W - 1 - t0) / NSLOTS) * NSLOTS) : 0; // last write wins
  const float* mrow = memory + ((size_t)l * NSLOTS + s) * D;
  const float* vrow = values + (size_t)t * D;

  float acoef = 0.f, bcoef = 1.0f;
  if (written) {
    const float* gw = gate_w + (size_t)l * D;
    double acc = 0.0;
    for (int j = tid; j < D; j += 256)
      acc += (double)vrow[j] * (double)gw[j];
    for (int off = 32; off; off >>= 1) acc += __shfl_down(acc, off, 64);
    __shared__ double wsum[4];
    if ((tid & 63) == 0) wsum[tid >> 6] = acc;
    __syncthreads();
    double dot = wsum[0] + wsum[1] + wsum[2] + wsum[3];
    float x = (float)dot + gate_b[l];
    float g = 1.0f / (1.0f + expf(-x));
    acoef = 0.1f * g; bcoef = 0.9f;
  }

  for (int j4 = tid; j4 < D / 4; j4 += 256) {
    float4 mv = ((const float4*)mrow)[j4];
    float4 vv = make_float4(0.f, 0.f, 0.f, 0.f);
    if (written) vv = ((const float4*)vrow)[j4];
    float ov[4];
    ov[0] = acoef * vv.x + bcoef * mv.x;
    ov[1] = acoef * vv.y + bcoef * mv.y;
    ov[2] = acoef * vv.z + bcoef * mv.z;
    ov[3] = acoef * vv.w + bcoef * mv.w;
    ((float4*)(ws_mem + (size_t)s * D))[j4] =
        make_float4(ov[0], ov[1], ov[2], ov[3]);
    unsigned short h[4], md[4];
#pragma unroll
    for (int e = 0; e < 4; ++e) {
      h[e] = bfrne(ov[e]);
      float f = __uint_as_float((unsigned)h[e] << 16);
      md[e] = bfrne(ov[e] - f);
    }
    uint2 hp = make_uint2((unsigned)h[0] | ((unsigned)h[1] << 16),
                          (unsigned)h[2] | ((unsigned)h[3] << 16));
    uint2 mp = make_uint2((unsigned)md[0] | ((unsigned)md[1] << 16),
                          (unsigned)md[2] | ((unsigned)md[3] << 16));
    ((uint2*)Mh)[(size_t)s * (D / 4) + j4] = hp;
    ((uint2*)Mm)[(size_t)s * (D / 4) + j4] = mp;
#pragma unroll
    for (int e = 0; e < 4; ++e) {
      Mth[(size_t)(j4 * 4 + e) * NSLOTS + s] = h[e];
      Mtm[(size_t)(j4 * 4 + e) * NSLOTS + s] = md[e];
    }
  }
}

// ---- Kernel B: partial scores, m97-style LDS-DMA staged GEMM ---------------
// grid = (TR/128) * 8 = 512 blocks x 256 thr. Block (qt,kq): q-rows qt*128..+128,
// K range kq*512..+512, all 128 slots. BK=32, 16 K-steps.
// LDS layouts are unit-transposed ([unit][row] of 16B units) so that
// global_load_lds linear dest order maps cleanly AND ds_read_b128 lanes spread
// uniformly (8 lanes per 16B span = minimum phases).
__global__ __launch_bounds__(256) void scores_kernel(
    const float* __restrict__ queries, const unsigned short* __restrict__ Mh,
    const unsigned short* __restrict__ Mm, float* __restrict__ part) {
  __shared__ float4 QsV[8 * 128];    // 16 KB: Q[row][u*4..u*4+4) at QsV[u*128+row]
  __shared__ bf16x8 MhV[4 * 128];    //  8 KB: Mh[slot][u*8..+8) at MhV[u*128+slot]
  __shared__ bf16x8 MmV[4 * 128];    //  8 KB

  const int tid = threadIdx.x, lane = tid & 63, w = tid >> 6;
  const int fr = lane & 15, fo = lane >> 4;
  const int qt = blockIdx.x >> 3, kq = blockIdx.x & 7;
  const int qbase = qt * 128;
  const int kbase = kq * 512;

  // staging source pointers (per-lane; advance by 32 elements per K-step)
  const float* qsrc[4];
#pragma unroll
  for (int i = 0; i < 4; ++i) {
    int idx = w * 256 + i * 64 + lane;          // 16B-unit index in Q tile
    int u = idx >> 7, row = idx & 127;
    qsrc[i] = queries + (size_t)(qbase + row) * D + kbase + u * 4;
  }
  const unsigned short *mhsrc[2], *mmsrc[2];
#pragma unroll
  for (int i = 0; i < 2; ++i) {
    int idx = w * 128 + i * 64 + lane;          // 16B-unit index in M tile
    int u = idx >> 7, slot = idx & 127;
    mhsrc[i] = Mh + (size_t)slot * D + kbase + u * 8;
    mmsrc[i] = Mm + (size_t)slot * D + kbase + u * 8;
  }

  f32x4 acc[2][8];
#pragma unroll
  for (int rg = 0; rg < 2; ++rg)
#pragma unroll
    for (int cg = 0; cg < 8; ++cg) acc[rg][cg] = (f32x4){0.f, 0.f, 0.f, 0.f};

  const int rowA = w * 32 + fr;   // wave's A-fragment base row (+rg*16)

  for (int s = 0; s < 16; ++s) {
    const int k0 = s * 32;        // element offset within the 512-wide K chunk
    // ---- stage via LDS-DMA (no VGPR round trip) ----
#pragma unroll
    for (int i = 0; i < 4; ++i)
      gload16(qsrc[i] + k0, &QsV[w * 256 + i * 64]);
#pragma unroll
    for (int i = 0; i < 2; ++i) {
      gload16(mhsrc[i] + k0, &MhV[w * 128 + i * 64]);
      gload16(mmsrc[i] + k0, &MmV[w * 128 + i * 64]);
    }
    __syncthreads();              // drains vmcnt before any LDS read

    // ---- compute ----
#pragma unroll
    for (int rg = 0; rg < 2; ++rg) {
      const int row = rowA + rg * 16;
      float4 a0 = QsV[(fo * 2 + 0) * 128 + row];
      float4 a1 = QsV[(fo * 2 + 1) * 128 + row];
      float qf[8] = {a0.x, a0.y, a0.z, a0.w, a1.x, a1.y, a1.z, a1.w};
      BV ah, am;
#pragma unroll
      for (int i = 0; i < 4; ++i) {
        unsigned u0 = __float_as_uint(qf[2 * i]);
        unsigned u1 = __float_as_uint(qf[2 * i + 1]);
        ah.u[i] = (u0 >> 16) | (u1 & 0xffff0000u);     // truncated hi
        float f0 = __uint_as_float(u0 & 0xffff0000u);
        float f1 = __uint_as_float(u1 & 0xffff0000u);
        unsigned d0 = __float_as_uint(qf[2 * i] - f0);
        unsigned d1 = __float_as_uint(qf[2 * i + 1] - f1);
        am.u[i] = (d0 >> 16) | (d1 & 0xffff0000u);     // truncated mid
      }
#pragma unroll
      for (int cg = 0; cg < 8; ++cg) {
        const int slot = cg * 16 + fr;
        bf16x8 bh = MhV[fo * 128 + slot];
        bf16x8 bm = MmV[fo * 128 + slot];
        acc[rg][cg] = __builtin_amdgcn_mfma_f32_16x16x32_bf16(am.v, bh, acc[rg][cg], 0, 0, 0);
        acc[rg][cg] = __builtin_amdgcn_mfma_f32_16x16x32_bf16(ah.v, bm, acc[rg][cg], 0, 0, 0);
        acc[rg][cg] = __builtin_amdgcn_mfma_f32_16x16x32_bf16(ah.v, bh, acc[rg][cg], 0, 0, 0);
      }
    }
    __syncthreads();              // protect LDS before next stage
  }

  float* op = part + ((size_t)kq * TR + qbase) * NSLOTS;
#pragma unroll
  for (int rg = 0; rg < 2; ++rg)
#pragma unroll
    for (int cg = 0; cg < 8; ++cg)
#pragma unroll
      for (int r = 0; r < 4; ++r)
        op[(size_t)(w * 32 + rg * 16 + fo * 4 + r) * NSLOTS + cg * 16 + fr] =
            acc[rg][cg][r];
}

// ---- Kernel C: wave-per-row reduce-partials -> top-k -> softmax -> A planes --
__device__ __forceinline__ unsigned mapf(float f) {
  unsigned u = __float_as_uint(f);
  return (u & 0x80000000u) ? ~u : (u | 0x80000000u);
}
__device__ __forceinline__ float unmapf(unsigned u) {
  return __uint_as_float((u & 0x80000000u) ? (u & 0x7fffffffu) : ~u);
}

__device__ __forceinline__ void wave_select(
    float va, float vb, int l, int k, int iters,
    float &m, float &sum, bool &sela, bool &selb, float &vkm1, float &vkk) {
  m = 0.f; sum = 0.f; sela = false; selb = false; vkm1 = 0.f; vkk = -3.4e38f;
  for (int it = 0; it < iters; ++it) {
    unsigned long long ka =
        ((unsigned long long)mapf(va) << 32) | (unsigned)(127 - l);
    unsigned long long kb =
        ((unsigned long long)mapf(vb) << 32) | (unsigned)(63 - l);
    unsigned long long key = ka > kb ? ka : kb;
#pragma unroll
    for (int off = 32; off; off >>= 1) {
      unsigned long long o = __shfl_xor(key, off, 64);
      if (o > key) key = o;
    }
    int idx = 127 - (int)(unsigned)(key & 0xffffffffULL);
    float val = unmapf((unsigned)(key >> 32));
    if (it == 0) m = val;
    if (it < k) sum += expf(val - m);
    if (it == k - 1) vkm1 = val;
    if (it == k) vkk = val;
    if (idx == l) { sela = sela || (it < k); va = -INFINITY; }
    if (idx == l + 64) { selb = selb || (it < k); vb = -INFINITY; }
  }
}

__device__ __forceinline__ float rescore_slot(const float* __restrict__ qrow,
                                              const float* __restrict__ mrow,
                                              int l) {
  double acc = 0.0;
#pragma unroll 4
  for (int c = 0; c < 16; ++c) {
    int j = c * 256 + l * 4;
    float4 qv = *(const float4*)(qrow + j);
    float4 mv = *(const float4*)(mrow + j);
    acc += (double)qv.x * (double)mv.x;
    acc += (double)qv.y * (double)mv.y;
    acc += (double)qv.z * (double)mv.z;
    acc += (double)qv.w * (double)mv.w;
  }
#pragma unroll
  for (int off = 32; off; off >>= 1) acc += __shfl_xor(acc, off, 64);
  return (float)(acc * 0.015625);
}

__global__ __launch_bounds__(256) void topk_kernel(
    const float* __restrict__ part, const float* __restrict__ ws_mem,
    const float* __restrict__ queries, const int* __restrict__ k_p,
    unsigned short* __restrict__ Ah, unsigned short* __restrict__ Am) {
  const int w = threadIdx.x >> 6, l = threadIdx.x & 63;
  const int row = blockIdx.x * 4 + w;
  int k = k_p[0];
  if (k < 1) k = 1;
  if (k > NSLOTS) k = NSLOTS;
  const int ksel = (k < NSLOTS) ? k + 1 : k;

  float origa = 0.f, origb = 0.f;
#pragma unroll
  for (int kq = 0; kq < 8; ++kq) {
    origa += part[((size_t)kq * TR + row) * NSLOTS + l];
    origb += part[((size_t)kq * TR + row) * NSLOTS + 64 + l];
  }
  origa *= 0.015625f;   // 1/sqrt(4096)
  origb *= 0.015625f;

  float m, sum, vkm1, vkk;
  bool sela, selb;
  wave_select(origa, origb, l, k, ksel, m, sum, sela, selb, vkm1, vkk);

  if (ksel > k && (vkm1 - vkk) < EPS_TRIG) {
    // exact fp64 rescore of boundary-window slots only (set membership fix)
    const float* qrow = queries + (size_t)row * D;
    float lo = vkk - WIN, hi = vkm1 + WIN;
    unsigned long long ba = __ballot(origa >= lo && origa <= hi);
    unsigned long long bb = __ballot(origb >= lo && origb <= hi);
    while (ba) {
      int s = __ffsll(ba) - 1; ba &= ba - 1;
      float ex = rescore_slot(qrow, ws_mem + (size_t)s * D, l);
      if (l == s) origa = ex;
    }
    while (bb) {
      int s = __ffsll(bb) - 1; bb &= bb - 1;
      float ex = rescore_slot(qrow, ws_mem + (size_t)(s + 64) * D, l);
      if (l == s) origb = ex;
    }
    wave_select(origa, origb, l, k, k, m, sum, sela, selb, vkm1, vkk);
  }

  const float inv = 1.0f / sum;
  float wa = sela ? expf(origa - m) * inv : 0.f;
  float wb = selb ? expf(origb - m) * inv : 0.f;

  unsigned short ha = bfrne(wa);
  unsigned short ma = bfrne(wa - __uint_as_float((unsigned)ha << 16));
  unsigned short hb = bfrne(wb);
  unsigned short mb = bfrne(wb - __uint_as_float((unsigned)hb << 16));
  Ah[(size_t)row * NSLOTS + l] = ha;
  Am[(size_t)row * NSLOTS + l] = ma;
  Ah[(size_t)row * NSLOTS + 64 + l] = hb;
  Am[(size_t)row * NSLOTS + 64 + l] = mb;
}

// ---- Kernel D: out = A @ mem_new as dense bf16-split GEMM (K=128) ----
__global__ __launch_bounds__(256) void gather_kernel(
    const unsigned short* __restrict__ Ah, const unsigned short* __restrict__ Am,
    const unsigned short* __restrict__ Mth, const unsigned short* __restrict__ Mtm,
    float* __restrict__ out) {
  const int tid = threadIdx.x, lane = tid & 63, w = tid >> 6;
  const int fr = lane & 15, fo = lane >> 4;
  const int rowblk = blockIdx.x >> 5, colblk = blockIdx.x & 31;
  const int r0 = rowblk * 64 + w * 16;

  const unsigned short* ap_h = Ah + (size_t)(r0 + fr) * NSLOTS + fo * 8;
  const unsigned short* ap_m = Am + (size_t)(r0 + fr) * NSLOTS + fo * 8;
  bf16x8 a_h[4], a_m[4];
#pragma unroll
  for (int c = 0; c < 4; ++c) {
    a_h[c] = *(const bf16x8*)(ap_h + c * 32);
    a_m[c] = *(const bf16x8*)(ap_m + c * 32);
  }

#pragma unroll 2
  for (int ct = 0; ct < 8; ++ct) {
    const int col = colblk * 128 + ct * 16 + fr;
    const unsigned short* bp_h = Mth + (size_t)col * NSLOTS + fo * 8;
    const unsigned short* bp_m = Mtm + (size_t)col * NSLOTS + fo * 8;
    f32x4 acc = {0.f, 0.f, 0.f, 0.f};
#pragma unroll
    for (int c = 0; c < 4; ++c) {
      bf16x8 bh = *(const bf16x8*)(bp_h + c * 32);
      bf16x8 bm = *(const bf16x8*)(bp_m + c * 32);
      acc = __builtin_amdgcn_mfma_f32_16x16x32_bf16(a_m[c], bh, acc, 0, 0, 0);
      acc = __builtin_amdgcn_mfma_f32_16x16x32_bf16(a_h[c], bm, acc, 0, 0, 0);
      acc = __builtin_amdgcn_mfma_f32_16x16x32_bf16(a_h[c], bh, acc, 0, 0, 0);
    }
#pragma unroll
    for (int r = 0; r < 4; ++r)
      out[(size_t)(r0 + fo * 4 + r) * D + col] = acc[r];
  }
}

extern "C" void kernel_launch(void* const* d_in, const int* in_sizes, int n_in,
                              void* d_out, int out_size, void* d_ws, size_t ws_size,
                              hipStream_t stream) {
  const float* values  = (const float*)d_in[0];
  const float* queries = (const float*)d_in[1];
  const float* memory  = (const float*)d_in[2];
  const float* gate_w  = (const float*)d_in[3];
  const float* gate_b  = (const float*)d_in[4];
  const int* layer_idx = (const int*)d_in[5];
  const int* k_p       = (const int*)d_in[6];
  const int* ptr_p     = (const int*)d_in[7];

  const int T_W = in_sizes[0] / D;   // 128
  const int T_R = in_sizes[1] / D;   // 8192

  float* ws_mem = (float*)d_ws;                              // 2 MiB
  float* part   = ws_mem + (size_t)NSLOTS * D;               // 8 planes, 32 MiB
  unsigned short* Mh  = (unsigned short*)(part + (size_t)8 * TR * NSLOTS);
  unsigned short* Mm  = Mh  + (size_t)NSLOTS * D;            // 1 MiB each
  unsigned short* Mth = Mm  + (size_t)NSLOTS * D;
  unsigned short* Mtm = Mth + (size_t)NSLOTS * D;
  unsigned short* Ah  = Mtm + (size_t)NSLOTS * D;            // 2 MiB each
  unsigned short* Am  = Ah  + (size_t)T_R * NSLOTS;

  update_mem_kernel<<<NSLOTS, 256, 0, stream>>>(
      values, memory, gate_w, gate_b, layer_idx, ptr_p, T_W,
      ws_mem, Mh, Mm, Mth, Mtm);
  scores_kernel<<<(T_R / 128) * 8, 256, 0, stream>>>(queries, Mh, Mm, part);
  topk_kernel<<<T_R / 4, 256, 0, stream>>>(part, ws_mem, queries, k_p, Ah, Am);
  gather_kernel<<<(T_R / 64) * 32, 256, 0, stream>>>(Ah, Am, Mth, Mtm,
                                                     (float*)d_out);
}

// Round 9
// 144.028 us; speedup vs baseline: 2.2481x; 1.5980x over previous
//
#include <hip/hip_runtime.h>
#include <math.h>

#define D 4096
#define NSLOTS 128
#define TR 8192
#define EPS_TRIG 5e-5f
#define WIN 2e-5f

typedef __attribute__((ext_vector_type(8))) short bf16x8;
typedef __attribute__((ext_vector_type(4))) float f32x4;

union BV { bf16x8 v; unsigned u[4]; };

__device__ __forceinline__ unsigned short bfrne(float x) {
  unsigned u = __float_as_uint(x);
  unsigned r = u + 0x7fffu + ((u >> 16) & 1u);   // round-to-nearest-even
  return (unsigned short)(r >> 16);
}

__device__ __forceinline__ void gload16(const void* gsrc, void* ldst) {
  __builtin_amdgcn_global_load_lds(
      (const __attribute__((address_space(1))) void*)gsrc,
      (__attribute__((address_space(3))) void*)ldst, 16, 0, 0);
}

// ---- Kernel A: EMA write + produce M bf16 hi/mid planes (row-major + T) ----
__global__ __launch_bounds__(256) void update_mem_kernel(
    const float* __restrict__ values, const float* __restrict__ memory,
    const float* __restrict__ gate_w, const float* __restrict__ gate_b,
    const int* __restrict__ layer_idx_p, const int* __restrict__ ptr_p,
    int T_W, float* __restrict__ ws_mem,
    unsigned short* __restrict__ Mh, unsigned short* __restrict__ Mm,
    unsigned short* __restrict__ Mth, unsigned short* __restrict__ Mtm) {
  const int l = layer_idx_p[0], p = ptr_p[0], s = blockIdx.x, tid = threadIdx.x;
  int t0 = ((s - p) % NSLOTS + NSLOTS) % NSLOTS;
  const bool written = (t0 < T_W);
  const int t = written ? (t0 + ((T_W - 1 - t0) / NSLOTS) * NSLOTS) : 0; // last write wins
  const float* mrow = memory + ((size_t)l * NSLOTS + s) * D;
  const float* vrow = values + (size_t)t * D;

  float acoef = 0.f, bcoef = 1.0f;
  if (written) {
    const float* gw = gate_w + (size_t)l * D;
    double acc = 0.0;
    for (int j = tid; j < D; j += 256)
      acc += (double)vrow[j] * (double)gw[j];
    for (int off = 32; off; off >>= 1) acc += __shfl_down(acc, off, 64);
    __shared__ double wsum[4];
    if ((tid & 63) == 0) wsum[tid >> 6] = acc;
    __syncthreads();
    double dot = wsum[0] + wsum[1] + wsum[2] + wsum[3];
    float x = (float)dot + gate_b[l];
    float g = 1.0f / (1.0f + expf(-x));
    acoef = 0.1f * g; bcoef = 0.9f;
  }

  for (int j4 = tid; j4 < D / 4; j4 += 256) {
    float4 mv = ((const float4*)mrow)[j4];
    float4 vv = make_float4(0.f, 0.f, 0.f, 0.f);
    if (written) vv = ((const float4*)vrow)[j4];
    float ov[4];
    ov[0] = acoef * vv.x + bcoef * mv.x;
    ov[1] = acoef * vv.y + bcoef * mv.y;
    ov[2] = acoef * vv.z + bcoef * mv.z;
    ov[3] = acoef * vv.w + bcoef * mv.w;
    ((float4*)(ws_mem + (size_t)s * D))[j4] =
        make_float4(ov[0], ov[1], ov[2], ov[3]);
    unsigned short h[4], md[4];
#pragma unroll
    for (int e = 0; e < 4; ++e) {
      h[e] = bfrne(ov[e]);
      float f = __uint_as_float((unsigned)h[e] << 16);
      md[e] = bfrne(ov[e] - f);
    }
    uint2 hp = make_uint2((unsigned)h[0] | ((unsigned)h[1] << 16),
                          (unsigned)h[2] | ((unsigned)h[3] << 16));
    uint2 mp = make_uint2((unsigned)md[0] | ((unsigned)md[1] << 16),
                          (unsigned)md[2] | ((unsigned)md[3] << 16));
    ((uint2*)Mh)[(size_t)s * (D / 4) + j4] = hp;
    ((uint2*)Mm)[(size_t)s * (D / 4) + j4] = mp;
#pragma unroll
    for (int e = 0; e < 4; ++e) {
      Mth[(size_t)(j4 * 4 + e) * NSLOTS + s] = h[e];
      Mtm[(size_t)(j4 * 4 + e) * NSLOTS + s] = md[e];
    }
  }
}

// ---- Kernel B: partial scores, m97-style LDS-DMA staged GEMM ---------------
// grid = (TR/128) * 8 = 512 blocks x 256 thr. Block (qt,kq): q-rows qt*128..+128,
// K range kq*512..+512, all 128 slots. BK=32, 16 K-steps.
__global__ __launch_bounds__(256) void scores_kernel(
    const float* __restrict__ queries, const unsigned short* __restrict__ Mh,
    const unsigned short* __restrict__ Mm, float* __restrict__ part) {
  __shared__ float4 QsV[8 * 128];    // 16 KB: Q[row][u*4..u*4+4) at QsV[u*128+row]
  __shared__ bf16x8 MhV[4 * 128];    //  8 KB: Mh[slot][u*8..+8) at MhV[u*128+slot]
  __shared__ bf16x8 MmV[4 * 128];    //  8 KB

  const int tid = threadIdx.x, lane = tid & 63, w = tid >> 6;
  const int fr = lane & 15, fo = lane >> 4;
  const int qt = blockIdx.x >> 3, kq = blockIdx.x & 7;
  const int qbase = qt * 128;
  const int kbase = kq * 512;

  const float* qsrc[4];
#pragma unroll
  for (int i = 0; i < 4; ++i) {
    int idx = w * 256 + i * 64 + lane;          // 16B-unit index in Q tile
    int u = idx >> 7, row = idx & 127;
    qsrc[i] = queries + (size_t)(qbase + row) * D + kbase + u * 4;
  }
  const unsigned short *mhsrc[2], *mmsrc[2];
#pragma unroll
  for (int i = 0; i < 2; ++i) {
    int idx = w * 128 + i * 64 + lane;          // 16B-unit index in M tile
    int u = idx >> 7, slot = idx & 127;
    mhsrc[i] = Mh + (size_t)slot * D + kbase + u * 8;
    mmsrc[i] = Mm + (size_t)slot * D + kbase + u * 8;
  }

  f32x4 acc[2][8];
#pragma unroll
  for (int rg = 0; rg < 2; ++rg)
#pragma unroll
    for (int cg = 0; cg < 8; ++cg) acc[rg][cg] = (f32x4){0.f, 0.f, 0.f, 0.f};

  const int rowA = w * 32 + fr;   // wave's A-fragment base row (+rg*16)

  for (int s = 0; s < 16; ++s) {
    const int k0 = s * 32;
#pragma unroll
    for (int i = 0; i < 4; ++i)
      gload16(qsrc[i] + k0, &QsV[w * 256 + i * 64]);
#pragma unroll
    for (int i = 0; i < 2; ++i) {
      gload16(mhsrc[i] + k0, &MhV[w * 128 + i * 64]);
      gload16(mmsrc[i] + k0, &MmV[w * 128 + i * 64]);
    }
    __syncthreads();

#pragma unroll
    for (int rg = 0; rg < 2; ++rg) {
      const int row = rowA + rg * 16;
      float4 a0 = QsV[(fo * 2 + 0) * 128 + row];
      float4 a1 = QsV[(fo * 2 + 1) * 128 + row];
      float qf[8] = {a0.x, a0.y, a0.z, a0.w, a1.x, a1.y, a1.z, a1.w};
      BV ah, am;
#pragma unroll
      for (int i = 0; i < 4; ++i) {
        unsigned u0 = __float_as_uint(qf[2 * i]);
        unsigned u1 = __float_as_uint(qf[2 * i + 1]);
        ah.u[i] = (u0 >> 16) | (u1 & 0xffff0000u);     // truncated hi
        float f0 = __uint_as_float(u0 & 0xffff0000u);
        float f1 = __uint_as_float(u1 & 0xffff0000u);
        unsigned d0 = __float_as_uint(qf[2 * i] - f0);
        unsigned d1 = __float_as_uint(qf[2 * i + 1] - f1);
        am.u[i] = (d0 >> 16) | (d1 & 0xffff0000u);     // truncated mid
      }
#pragma unroll
      for (int cg = 0; cg < 8; ++cg) {
        const int slot = cg * 16 + fr;
        bf16x8 bh = MhV[fo * 128 + slot];
        bf16x8 bm = MmV[fo * 128 + slot];
        acc[rg][cg] = __builtin_amdgcn_mfma_f32_16x16x32_bf16(am.v, bh, acc[rg][cg], 0, 0, 0);
        acc[rg][cg] = __builtin_amdgcn_mfma_f32_16x16x32_bf16(ah.v, bm, acc[rg][cg], 0, 0, 0);
        acc[rg][cg] = __builtin_amdgcn_mfma_f32_16x16x32_bf16(ah.v, bh, acc[rg][cg], 0, 0, 0);
      }
    }
    __syncthreads();
  }

  float* op = part + ((size_t)kq * TR + qbase) * NSLOTS;
#pragma unroll
  for (int rg = 0; rg < 2; ++rg)
#pragma unroll
    for (int cg = 0; cg < 8; ++cg)
#pragma unroll
      for (int r = 0; r < 4; ++r)
        op[(size_t)(w * 32 + rg * 16 + fo * 4 + r) * NSLOTS + cg * 16 + fr] =
            acc[rg][cg][r];
}

// ---- Kernel C: wave-per-row reduce-partials -> top-k -> softmax -> A planes --
__device__ __forceinline__ unsigned mapf(float f) {
  unsigned u = __float_as_uint(f);
  return (u & 0x80000000u) ? ~u : (u | 0x80000000u);
}
__device__ __forceinline__ float unmapf(unsigned u) {
  return __uint_as_float((u & 0x80000000u) ? (u & 0x7fffffffu) : ~u);
}

__device__ __forceinline__ void wave_select(
    float va, float vb, int l, int k, int iters,
    float &m, float &sum, bool &sela, bool &selb, float &vkm1, float &vkk) {
  m = 0.f; sum = 0.f; sela = false; selb = false; vkm1 = 0.f; vkk = -3.4e38f;
  for (int it = 0; it < iters; ++it) {
    unsigned long long ka =
        ((unsigned long long)mapf(va) << 32) | (unsigned)(127 - l);
    unsigned long long kb =
        ((unsigned long long)mapf(vb) << 32) | (unsigned)(63 - l);
    unsigned long long key = ka > kb ? ka : kb;
#pragma unroll
    for (int off = 32; off; off >>= 1) {
      unsigned long long o = __shfl_xor(key, off, 64);
      if (o > key) key = o;
    }
    int idx = 127 - (int)(unsigned)(key & 0xffffffffULL);
    float val = unmapf((unsigned)(key >> 32));
    if (it == 0) m = val;
    if (it < k) sum += expf(val - m);
    if (it == k - 1) vkm1 = val;
    if (it == k) vkk = val;
    if (idx == l) { sela = sela || (it < k); va = -INFINITY; }
    if (idx == l + 64) { selb = selb || (it < k); vb = -INFINITY; }
  }
}

__device__ __forceinline__ float rescore_slot(const float* __restrict__ qrow,
                                              const float* __restrict__ mrow,
                                              int l) {
  double acc = 0.0;
#pragma unroll 4
  for (int c = 0; c < 16; ++c) {
    int j = c * 256 + l * 4;
    float4 qv = *(const float4*)(qrow + j);
    float4 mv = *(const float4*)(mrow + j);
    acc += (double)qv.x * (double)mv.x;
    acc += (double)qv.y * (double)mv.y;
    acc += (double)qv.z * (double)mv.z;
    acc += (double)qv.w * (double)mv.w;
  }
#pragma unroll
  for (int off = 32; off; off >>= 1) acc += __shfl_xor(acc, off, 64);
  return (float)(acc * 0.015625);
}

__global__ __launch_bounds__(256) void topk_kernel(
    const float* __restrict__ part, const float* __restrict__ ws_mem,
    const float* __restrict__ queries, const int* __restrict__ k_p,
    unsigned short* __restrict__ Ah, unsigned short* __restrict__ Am) {
  const int w = threadIdx.x >> 6, l = threadIdx.x & 63;
  const int row = blockIdx.x * 4 + w;
  int k = k_p[0];
  if (k < 1) k = 1;
  if (k > NSLOTS) k = NSLOTS;
  const int ksel = (k < NSLOTS) ? k + 1 : k;

  float origa = 0.f, origb = 0.f;
#pragma unroll
  for (int kq = 0; kq < 8; ++kq) {
    origa += part[((size_t)kq * TR + row) * NSLOTS + l];
    origb += part[((size_t)kq * TR + row) * NSLOTS + 64 + l];
  }
  origa *= 0.015625f;   // 1/sqrt(4096)
  origb *= 0.015625f;

  float m, sum, vkm1, vkk;
  bool sela, selb;
  wave_select(origa, origb, l, k, ksel, m, sum, sela, selb, vkm1, vkk);

  if (ksel > k && (vkm1 - vkk) < EPS_TRIG) {
    const float* qrow = queries + (size_t)row * D;
    float lo = vkk - WIN, hi = vkm1 + WIN;
    unsigned long long ba = __ballot(origa >= lo && origa <= hi);
    unsigned long long bb = __ballot(origb >= lo && origb <= hi);
    while (ba) {
      int s = __ffsll(ba) - 1; ba &= ba - 1;
      float ex = rescore_slot(qrow, ws_mem + (size_t)s * D, l);
      if (l == s) origa = ex;
    }
    while (bb) {
      int s = __ffsll(bb) - 1; bb &= bb - 1;
      float ex = rescore_slot(qrow, ws_mem + (size_t)(s + 64) * D, l);
      if (l == s) origb = ex;
    }
    wave_select(origa, origb, l, k, k, m, sum, sela, selb, vkm1, vkk);
  }

  const float inv = 1.0f / sum;
  float wa = sela ? expf(origa - m) * inv : 0.f;
  float wb = selb ? expf(origb - m) * inv : 0.f;

  unsigned short ha = bfrne(wa);
  unsigned short ma = bfrne(wa - __uint_as_float((unsigned)ha << 16));
  unsigned short hb = bfrne(wb);
  unsigned short mb = bfrne(wb - __uint_as_float((unsigned)hb << 16));
  Ah[(size_t)row * NSLOTS + l] = ha;
  Am[(size_t)row * NSLOTS + l] = ma;
  Ah[(size_t)row * NSLOTS + 64 + l] = hb;
  Am[(size_t)row * NSLOTS + 64 + l] = mb;
}

// ---- Kernel D: out = A @ mem_new, LDS-DMA staged, swizzled, coalesced ------
// grid = (TR/64) * (D/64) = 8192 blocks. Block: 64 rows x 64 cols, K=128 fully
// staged. Wave w DMA-stages region w (Ah/Am rows | Mth/Mtm cols), pre-swizzled
// source so reads use byte ^= (row&7)<<4 (guide G4 recipe for [64][128] bf16).
// Waves 2x2 over the tile. Epilogue via padded LDS f32 -> float4 stores.
__global__ __launch_bounds__(256) void gather_kernel(
    const unsigned short* __restrict__ Ah, const unsigned short* __restrict__ Am,
    const unsigned short* __restrict__ Mth, const unsigned short* __restrict__ Mtm,
    float* __restrict__ out) {
  __shared__ char lds[65536];   // 16K each: Ah | Am | Bh | Bm; epilogue aliases
  const int tid = threadIdx.x, lane = tid & 63, w = tid >> 6;
  const int fr = lane & 15, fo = lane >> 4;
  const int rowblk = blockIdx.x >> 6, colblk = blockIdx.x & 63;
  const int r0 = rowblk * 64, c0 = colblk * 64;

  // ---- stage 64 KB via LDS-DMA; wave w stages region w ----
  const unsigned short* srcbase =
      (w == 0) ? Ah + (size_t)r0 * NSLOTS :
      (w == 1) ? Am + (size_t)r0 * NSLOTS :
      (w == 2) ? Mth + (size_t)c0 * NSLOTS :
                 Mtm + (size_t)c0 * NSLOTS;
#pragma unroll
  for (int i = 0; i < 16; ++i) {
    int dl = i * 64 + lane;            // local 16B-unit idx within region
    int row = dl >> 4, u = dl & 15;
    int su = u ^ (row & 7);            // pre-swizzled source unit
    gload16(srcbase + (size_t)row * NSLOTS + su * 8,
            lds + w * 16384 + i * 1024);
  }
  __syncthreads();

  const int rw = w >> 1, cw = w & 1;
  f32x4 acc[2][2];
#pragma unroll
  for (int rg = 0; rg < 2; ++rg)
#pragma unroll
    for (int cg = 0; cg < 2; ++cg) acc[rg][cg] = (f32x4){0.f, 0.f, 0.f, 0.f};

#pragma unroll
  for (int c = 0; c < 4; ++c) {
    bf16x8 ah_[2], am_[2], bh_[2], bm_[2];
#pragma unroll
    for (int rg = 0; rg < 2; ++rg) {
      int row = rw * 32 + rg * 16 + fr;
      int off = row * 256 + ((c * 64 + fo * 16) ^ ((row & 7) << 4));
      ah_[rg] = *(const bf16x8*)(lds + off);
      am_[rg] = *(const bf16x8*)(lds + 16384 + off);
    }
#pragma unroll
    for (int cg = 0; cg < 2; ++cg) {
      int col = cw * 32 + cg * 16 + fr;
      int off = col * 256 + ((c * 64 + fo * 16) ^ ((col & 7) << 4));
      bh_[cg] = *(const bf16x8*)(lds + 32768 + off);
      bm_[cg] = *(const bf16x8*)(lds + 49152 + off);
    }
#pragma unroll
    for (int rg = 0; rg < 2; ++rg)
#pragma unroll
      for (int cg = 0; cg < 2; ++cg) {
        acc[rg][cg] = __builtin_amdgcn_mfma_f32_16x16x32_bf16(am_[rg], bh_[cg], acc[rg][cg], 0, 0, 0);
        acc[rg][cg] = __builtin_amdgcn_mfma_f32_16x16x32_bf16(ah_[rg], bm_[cg], acc[rg][cg], 0, 0, 0);
        acc[rg][cg] = __builtin_amdgcn_mfma_f32_16x16x32_bf16(ah_[rg], bh_[cg], acc[rg][cg], 0, 0, 0);
      }
  }
  __syncthreads();   // all LDS reads done before O aliases the buffer

  // ---- epilogue: acc -> padded LDS f32 [64][132] -> coalesced float4 stores
  float* O = (float*)lds;
#pragma unroll
  for (int rg = 0; rg < 2; ++rg)
#pragma unroll
    for (int cg = 0; cg < 2; ++cg)
#pragma unroll
      for (int r = 0; r < 4; ++r)
        O[(rw * 32 + rg * 16 + fo * 4 + r) * 132 + cw * 32 + cg * 16 + fr] =
            acc[rg][cg][r];
  __syncthreads();

#pragma unroll
  for (int i = 0; i < 4; ++i) {
    int idx = tid + i * 256;       // float4 unit: 64 rows x 16 units
    int row = idx >> 4, c4 = idx & 15;
    float4 v = *(const float4*)(O + row * 132 + c4 * 4);
    *(float4*)(out + (size_t)(r0 + row) * D + c0 + c4 * 4) = v;
  }
}

extern "C" void kernel_launch(void* const* d_in, const int* in_sizes, int n_in,
                              void* d_out, int out_size, void* d_ws, size_t ws_size,
                              hipStream_t stream) {
  const float* values  = (const float*)d_in[0];
  const float* queries = (const float*)d_in[1];
  const float* memory  = (const float*)d_in[2];
  const float* gate_w  = (const float*)d_in[3];
  const float* gate_b  = (const float*)d_in[4];
  const int* layer_idx = (const int*)d_in[5];
  const int* k_p       = (const int*)d_in[6];
  const int* ptr_p     = (const int*)d_in[7];

  const int T_W = in_sizes[0] / D;   // 128
  const int T_R = in_sizes[1] / D;   // 8192

  float* ws_mem = (float*)d_ws;                              // 2 MiB
  float* part   = ws_mem + (size_t)NSLOTS * D;               // 8 planes, 32 MiB
  unsigned short* Mh  = (unsigned short*)(part + (size_t)8 * TR * NSLOTS);
  unsigned short* Mm  = Mh  + (size_t)NSLOTS * D;            // 1 MiB each
  unsigned short* Mth = Mm  + (size_t)NSLOTS * D;
  unsigned short* Mtm = Mth + (size_t)NSLOTS * D;
  unsigned short* Ah  = Mtm + (size_t)NSLOTS * D;            // 2 MiB each
  unsigned short* Am  = Ah  + (size_t)T_R * NSLOTS;

  update_mem_kernel<<<NSLOTS, 256, 0, stream>>>(
      values, memory, gate_w, gate_b, layer_idx, ptr_p, T_W,
      ws_mem, Mh, Mm, Mth, Mtm);
  scores_kernel<<<(T_R / 128) * 8, 256, 0, stream>>>(queries, Mh, Mm, part);
  topk_kernel<<<T_R / 4, 256, 0, stream>>>(part, ws_mem, queries, k_p, Ah, Am);
  gather_kernel<<<(T_R / 64) * (D / 64), 256, 0, stream>>>(Ah, Am, Mth, Mtm,
                                                           (float*)d_out);
}